// Round 4
// baseline (140.993 us; speedup 1.0000x reference)
//
#include <hip/hip_runtime.h>

#define NB   4096
#define SS   102
#define SSP  104
#define HID  8
#define NH   2
#define HD   4
#define RS   0.72134752044448170368f   // 0.5 * log2(e): score scale folded into q

typedef float v2f __attribute__((ext_vector_type(2)));

// K/V row permutation, bijective on [0,104): keys 8j+w land at 13w+j ->
// a wave's 4 key-residue lanes read 4 bank-spread addresses.
__device__ __forceinline__ int PIDX(int r) { return (r & 7) * 13 + (r >> 3); }

template<int CTRL>
__device__ __forceinline__ float dppf(float x) {
    return __builtin_bit_cast(float,
        __builtin_amdgcn_mov_dpp(__builtin_bit_cast(int, x), CTRL, 0xF, 0xF, true));
}
template<int CTRL>
__device__ __forceinline__ v2f dpp2(v2f x) {
    v2f r; r.x = dppf<CTRL>(x.x); r.y = dppf<CTRL>(x.y); return r;
}

// 8 projected dims for 2 rows (v2f across rows). W is a wave-uniform kernel-arg
// pointer with compile-time indices -> weights come in via s_load (SGPRs).
__device__ __forceinline__ void proj8(const float4& a0, const float4& a1,
                                      const float4& b0, const float4& b1,
                                      const float* __restrict__ W, v2f x[8]) {
    v2f in[8] = { {a0.x,b0.x},{a0.y,b0.y},{a0.z,b0.z},{a0.w,b0.w},
                  {a1.x,b1.x},{a1.y,b1.y},{a1.z,b1.z},{a1.w,b1.w} };
#pragma unroll
    for (int i = 0; i < 8; ++i) {
        v2f acc = in[0] * W[i*8+0];
#pragma unroll
        for (int j = 1; j < 8; ++j) acc += in[j] * W[i*8+j];
        x[i] = acc;
    }
}

// LDS (~13.3 KB):
//  sQ : [2 heads][52 pairs][2 float4]  rotated+pre-scaled q, LINEAR pair slots
//       (round-2 layout: measured 139k conflicts vs 311k with PJ permute).
//       float4 2p = dims 0,1 x rows {2p,2p+1}; 2p+1 = dims 2,3.  pair 51 = zero pad.
//  sK : [2][PIDX(row)][4] rotated k (rows 102,103 zero pad)
//  sV : [2][PIDX(row)][4] projected v (rows 102,103 zero pad)
//  sC : [2][row][4] head-combined attention output, linear rows
__global__ __launch_bounds__(256) void mha_fused_kernel(
    const float* __restrict__ query, const float* __restrict__ key,
    const float* __restrict__ value, const float* __restrict__ wq,
    const float* __restrict__ wk, const float* __restrict__ wv,
    const float* __restrict__ wo, float* __restrict__ out)
{
    __shared__ float sQ[NH * 52 * 8];       // 832 floats
    __shared__ float sK[NH * SSP * HD];     // 832
    __shared__ float sV[NH * SSP * HD];     // 832
    __shared__ float sC[NH * SSP * HD];     // 832

    const int t    = threadIdx.x;
    const int b    = blockIdx.x;
    const int wid  = t >> 6;
    const int lane = t & 63;

    // ---------------- phase 0: issue global row loads; zero pads (wave 3) ----------------
    float4 a0, a1, b0, b1;
    if (wid < 3 && lane < 51) {
        const float* src = (wid == 0) ? query : (wid == 1) ? key : value;
        const float4* s4 = (const float4*)(src + (size_t)b * (SS * HID));
        a0 = s4[4*lane]; a1 = s4[4*lane+1]; b0 = s4[4*lane+2]; b1 = s4[4*lane+3];
    }
    if (t >= 208) {
        const int z = t - 208;                 // 0..47
        if (z < 16) {                          // q pad pair 51 (rows 102,103), both heads
            sQ[(z >> 3) * 416 + 408 + (z & 7)] = 0.f;
        } else {                               // k/v pad rows 102,103
            const int rem = z & 15;
            const int h = rem >> 3, r = SS + ((rem >> 2) & 1), d = rem & 3;
            float* dst = (z < 32) ? sK : sV;
            dst[(h * SSP + PIDX(r)) * HD + d] = 0.f;
        }
    }
    // NO barrier: phase 1 depends only on this lane's registers + SGPR weights;
    // pad writes are ordered by the barrier after phase 1 (addresses disjoint).

    // ---------------- phase 1: projections (wave0: q+rot, wave1: k+rot, wave2: v) ----------
    if (wid < 3 && lane < 51) {
        const int r0 = 2 * lane;
        // per-lane fast trig (waves 0,1) — overlaps the global-load latency
        v2f sn, cs;
        if (wid < 2) {
            const float f0 = (float)r0, f1 = (float)(r0 + 1);
            sn = (v2f){ __sinf(f0), __sinf(f1) };
            cs = (v2f){ __cosf(f0), __cosf(f1) };
            if (wid == 0) { sn *= RS; cs *= RS; }
        }
        v2f x[8];
        if (wid == 0)      proj8(a0, a1, b0, b1, wq, x);
        else if (wid == 1) proj8(a0, a1, b0, b1, wk, x);
        else               proj8(a0, a1, b0, b1, wv, x);

        if (wid < 2) {
            // reference broadcast quirk: head0 scaled by sin(s), head1 by cos(s);
            // pair: e' = (e - o)*w, o' = (o + e)*w.  q additionally folds 0.5*log2(e).
            const v2f y0 = (x[0]-x[1])*sn, y1 = (x[1]+x[0])*sn;
            const v2f y2 = (x[2]-x[3])*sn, y3 = (x[3]+x[2])*sn;
            const v2f y4 = (x[4]-x[5])*cs, y5 = (x[5]+x[4])*cs;
            const v2f y6 = (x[6]-x[7])*cs, y7 = (x[7]+x[6])*cs;
            if (wid == 0) {
                const int p = lane;                 // LINEAR pair slot
                float4* d = (float4*)sQ;
                d[2*p]       = make_float4(y0.x, y0.y, y1.x, y1.y);
                d[2*p+1]     = make_float4(y2.x, y2.y, y3.x, y3.y);
                d[104+2*p]   = make_float4(y4.x, y4.y, y5.x, y5.y);
                d[104+2*p+1] = make_float4(y6.x, y6.y, y7.x, y7.y);
            } else {
                const int i0 = PIDX(r0), i1 = PIDX(r0 + 1);
                float4* d = (float4*)sK;
                d[i0]      = make_float4(y0.x, y1.x, y2.x, y3.x);
                d[SSP+i0]  = make_float4(y4.x, y5.x, y6.x, y7.x);
                d[i1]      = make_float4(y0.y, y1.y, y2.y, y3.y);
                d[SSP+i1]  = make_float4(y4.y, y5.y, y6.y, y7.y);
            }
        } else {
            const int i0 = PIDX(r0), i1 = PIDX(r0 + 1);
            float4* d = (float4*)sV;
            d[i0]      = make_float4(x[0].x, x[1].x, x[2].x, x[3].x);
            d[SSP+i0]  = make_float4(x[4].x, x[5].x, x[6].x, x[7].x);
            d[i1]      = make_float4(x[0].y, x[1].y, x[2].y, x[3].y);
            d[SSP+i1]  = make_float4(x[4].y, x[5].y, x[6].y, x[7].y);
        }
    }
    __syncthreads();

    // ---------------- phase 2: attention, ALL 4 waves. wave = (head, q-half) -------------
    // lane = (qp, w): qp = lane>>2 (0..12) owns q-pairs {qh*26+2qp, +1} (4 rows);
    // w = lane&3 owns keys == w (mod 4).  FULLY UNROLLED j-loop with explicit 2-deep
    // load rotation: after unroll the rotation is pure SSA renaming, so the scheduler
    // keeps ~8-12 float4 loads in flight instead of re-rolling into a serial chain
    // (round-3 failure mode: VGPR pinned at 36 = bare accumulator state).
    const int qp = lane >> 2, w = lane & 3;
    if (qp < 13) {
        const int h  = wid >> 1;
        const int qh = wid & 1;
        const int p0 = qh * 26 + 2 * qp;          // first of 2 pairs
        v2f q[2][4];
        {
            const float4* Q4 = (const float4*)sQ + h * 104;
#pragma unroll
            for (int P = 0; P < 2; ++P) {
                const float4 f0 = Q4[2*(p0+P)];
                const float4 f1 = Q4[2*(p0+P)+1];
                q[P][0] = (v2f){f0.x, f0.y}; q[P][1] = (v2f){f0.z, f0.w};
                q[P][2] = (v2f){f1.x, f1.y}; q[P][3] = (v2f){f1.z, f1.w};
            }
        }
        v2f acc[2][4], l[2];
#pragma unroll
        for (int P = 0; P < 2; ++P) {
            l[P] = (v2f){0.f, 0.f};
#pragma unroll
            for (int d = 0; d < 4; ++d) acc[P][d] = (v2f){0.f, 0.f};
        }
        const float4* Ka = (const float4*)sK + h*SSP + 13*w;   // keys 8j+w   -> PIDX = 13w+j
        const float4* Kb = Ka + 52;                            // keys 8j+4+w -> PIDX = 13(w+4)+j
        const float4* Va = (const float4*)sV + h*SSP + 13*w;
        const float4* Vb = Va + 52;
#define BODY(KA, KB, VA, VB) { \
            _Pragma("unroll") \
            for (int P = 0; P < 2; ++P) { \
                v2f s = q[P][0]*(KA).x + q[P][1]*(KA).y + q[P][2]*(KA).z + q[P][3]*(KA).w; \
                v2f p; p.x = __builtin_amdgcn_exp2f(s.x); p.y = __builtin_amdgcn_exp2f(s.y); \
                l[P] += p; \
                acc[P][0] += p*(VA).x; acc[P][1] += p*(VA).y; \
                acc[P][2] += p*(VA).z; acc[P][3] += p*(VA).w; \
            } \
            _Pragma("unroll") \
            for (int P = 0; P < 2; ++P) { \
                v2f s = q[P][0]*(KB).x + q[P][1]*(KB).y + q[P][2]*(KB).z + q[P][3]*(KB).w; \
                v2f p; p.x = __builtin_amdgcn_exp2f(s.x); p.y = __builtin_amdgcn_exp2f(s.y); \
                l[P] += p; \
                acc[P][0] += p*(VB).x; acc[P][1] += p*(VB).y; \
                acc[P][2] += p*(VB).z; acc[P][3] += p*(VB).w; \
            } \
        }
        float4 cka = Ka[0], ckb = Kb[0], cva = Va[0], cvb = Vb[0];
        float4 nka = Ka[1], nkb = Kb[1], nva = Va[1], nvb = Vb[1];
#pragma unroll
        for (int j = 0; j < 13; ++j) {
            float4 fka, fkb, fva, fvb;
            if (j < 11) { fka = Ka[j+2]; fkb = Kb[j+2]; fva = Va[j+2]; fvb = Vb[j+2]; }
            BODY(cka, ckb, cva, cvb);
            cka = nka; ckb = nkb; cva = nva; cvb = nvb;
            if (j < 11) { nka = fka; nkb = fkb; nva = fva; nvb = fvb; }
        }
#undef BODY
        // pad keys 102,103 (zero K rows, exp2(0)=1) landed in residues w=2,3 via Kb
        if (w >= 2) { l[0] -= (v2f){1.f, 1.f}; l[1] -= (v2f){1.f, 1.f}; }
        // quad butterfly over the 4 key residues (pure VALU, no LDS round-trip)
#pragma unroll
        for (int P = 0; P < 2; ++P) {
            l[P] += dpp2<0xB1>(l[P]);                       // quad_perm [1,0,3,2]
#pragma unroll
            for (int d = 0; d < 4; ++d) acc[P][d] += dpp2<0xB1>(acc[P][d]);
        }
#pragma unroll
        for (int P = 0; P < 2; ++P) {
            l[P] += dpp2<0x4E>(l[P]);                       // quad_perm [2,3,0,1]
#pragma unroll
            for (int d = 0; d < 4; ++d) acc[P][d] += dpp2<0x4E>(acc[P][d]);
        }
        // lane w==0 writes pair 0, w==1 writes pair 1 (static branches)
        float4* comb = (float4*)sC + h * SSP;
#define WRITE_PAIR(P) { \
            const int r0 = 2 * (p0 + (P)); \
            if (r0 < SS) { \
                const float ix = 1.f / l[P].x; \
                comb[r0] = make_float4(acc[P][0].x*ix, acc[P][1].x*ix, \
                                       acc[P][2].x*ix, acc[P][3].x*ix); \
            } \
            if (r0 + 1 < SS) { \
                const float iy = 1.f / l[P].y; \
                comb[r0+1] = make_float4(acc[P][0].y*iy, acc[P][1].y*iy, \
                                         acc[P][2].y*iy, acc[P][3].y*iy); \
            } \
        }
        if      (w == 0) WRITE_PAIR(0)
        else if (w == 1) WRITE_PAIR(1)
#undef WRITE_PAIR
    }
    __syncthreads();

    // ---------------- phase 3: output projection (wo in SGPRs) ----------------
    const int row = wid * 26 + lane;
    if (lane < 26 && row < SS) {
        const float4 c0 = ((const float4*)sC)[row];        // head 0
        const float4 c1 = ((const float4*)sC)[SSP + row];  // head 1
        float o[8];
#pragma unroll
        for (int i = 0; i < 8; ++i) {
            const float* wr = wo + i*8;
            o[i] = c0.x*wr[0] + c0.y*wr[1] + c0.z*wr[2] + c0.w*wr[3]
                 + c1.x*wr[4] + c1.y*wr[5] + c1.z*wr[6] + c1.w*wr[7];
        }
        float4* o4 = (float4*)(out + (size_t)b * (SS * HID) + row * HID);
        o4[0] = make_float4(o[0], o[1], o[2], o[3]);
        o4[1] = make_float4(o[4], o[5], o[6], o[7]);
    }
}

extern "C" void kernel_launch(void* const* d_in, const int* in_sizes, int n_in,
                              void* d_out, int out_size, void* d_ws, size_t ws_size,
                              hipStream_t stream) {
    const float* query = (const float*)d_in[0];
    const float* key   = (const float*)d_in[1];
    const float* value = (const float*)d_in[2];
    const float* wq    = (const float*)d_in[3];
    const float* wk    = (const float*)d_in[4];
    const float* wv    = (const float*)d_in[5];
    const float* wo    = (const float*)d_in[6];
    float* out = (float*)d_out;
    mha_fused_kernel<<<NB, 256, 0, stream>>>(query, key, value, wq, wk, wv, wo, out);
}

// Round 5
// 129.777 us; speedup vs baseline: 1.0864x; 1.0864x over previous
//
#include <hip/hip_runtime.h>

#define NB   4096
#define SS   102
#define SSP  104
#define HID  8
#define NH   2
#define HD   4
#define VOFF (NH * SSP * HD)   // 832 floats: V region starts here inside sKV
#define RS   0.72134752044448170368f   // 0.5 * log2(e): score scale folded into q

typedef float v2f __attribute__((ext_vector_type(2)));
typedef float v4f __attribute__((ext_vector_type(4)));

// K/V row permutation, bijective on [0,104): keys 8j+w land at 13w+j ->
// a wave's 4 key-residue lanes read 4 bank-spread addresses.
__device__ __forceinline__ int PIDX(int r) { return (r & 7) * 13 + (r >> 3); }

template<int CTRL>
__device__ __forceinline__ float dppf(float x) {
    return __builtin_bit_cast(float,
        __builtin_amdgcn_mov_dpp(__builtin_bit_cast(int, x), CTRL, 0xF, 0xF, true));
}
template<int CTRL>
__device__ __forceinline__ v2f dpp2(v2f x) {
    v2f r; r.x = dppf<CTRL>(x.x); r.y = dppf<CTRL>(x.y); return r;
}

// 8 projected dims for 2 rows (v2f across rows). W is a wave-uniform kernel-arg
// pointer with compile-time indices -> weights come in via s_load (SGPRs).
__device__ __forceinline__ void proj8(const float4& a0, const float4& a1,
                                      const float4& b0, const float4& b1,
                                      const float* __restrict__ W, v2f x[8]) {
    v2f in[8] = { {a0.x,b0.x},{a0.y,b0.y},{a0.z,b0.z},{a0.w,b0.w},
                  {a1.x,b1.x},{a1.y,b1.y},{a1.z,b1.z},{a1.w,b1.w} };
#pragma unroll
    for (int i = 0; i < 8; ++i) {
        v2f acc = in[0] * W[i*8+0];
#pragma unroll
        for (int j = 1; j < 8; ++j) acc += in[j] * W[i*8+j];
        x[i] = acc;
    }
}

// LDS (~13.3 KB):
//  sQ  : [2 heads][52 pairs][2 float4]  rotated+pre-scaled q, LINEAR pair slots.
//        float4 2p = dims 0,1 x rows {2p,2p+1}; 2p+1 = dims 2,3.  pair 51 = zero pad.
//  sKV : K at [0..832) floats as [2][PIDX(row)][4]; V at [832..1664) same layout.
//        Rows 102,103 zero-padded.  Single array so phase-2 inline-asm ds_reads use
//        one base VGPR + immediate offsets (Kb:+832B, Va:+3328B, Vb:+4160B).
//  sC  : [2][row][4] head-combined attention output, linear rows
__global__ __launch_bounds__(256) void mha_fused_kernel(
    const float* __restrict__ query, const float* __restrict__ key,
    const float* __restrict__ value, const float* __restrict__ wq,
    const float* __restrict__ wk, const float* __restrict__ wv,
    const float* __restrict__ wo, float* __restrict__ out)
{
    __shared__ float sQ[NH * 52 * 8];       // 832 floats
    __shared__ float sKV[2 * NH * SSP * HD];// 1664 floats (K then V)
    __shared__ float sC[NH * SSP * HD];     // 832

    const int t    = threadIdx.x;
    const int b    = blockIdx.x;
    const int wid  = t >> 6;
    const int lane = t & 63;

    // ---------------- phase 0: issue global row loads; zero pads (wave 3) ----------------
    float4 a0, a1, b0, b1;
    if (wid < 3 && lane < 51) {
        const float* src = (wid == 0) ? query : (wid == 1) ? key : value;
        const float4* s4 = (const float4*)(src + (size_t)b * (SS * HID));
        a0 = s4[4*lane]; a1 = s4[4*lane+1]; b0 = s4[4*lane+2]; b1 = s4[4*lane+3];
    }
    if (t >= 208) {
        const int z = t - 208;                 // 0..47
        if (z < 16) {                          // q pad pair 51 (rows 102,103), both heads
            sQ[(z >> 3) * 416 + 408 + (z & 7)] = 0.f;
        } else {                               // k/v pad rows 102,103
            const int rem = z & 15;
            const int h = rem >> 3, r = SS + ((rem >> 2) & 1), d = rem & 3;
            const int voff = (z < 32) ? 0 : VOFF;
            sKV[voff + (h * SSP + PIDX(r)) * HD + d] = 0.f;
        }
    }
    // NO barrier: phase 1 depends only on this lane's registers + SGPR weights.

    // ---------------- phase 1: projections (wave0: q+rot, wave1: k+rot, wave2: v) ----------
    if (wid < 3 && lane < 51) {
        const int r0 = 2 * lane;
        v2f sn, cs;
        if (wid < 2) {
            const float f0 = (float)r0, f1 = (float)(r0 + 1);
            sn = (v2f){ sinf(f0), sinf(f1) };
            cs = (v2f){ cosf(f0), cosf(f1) };
            if (wid == 0) { sn *= RS; cs *= RS; }
        }
        v2f x[8];
        if (wid == 0)      proj8(a0, a1, b0, b1, wq, x);
        else if (wid == 1) proj8(a0, a1, b0, b1, wk, x);
        else               proj8(a0, a1, b0, b1, wv, x);

        if (wid < 2) {
            // reference broadcast quirk: head0 scaled by sin(s), head1 by cos(s);
            // pair: e' = (e - o)*w, o' = (o + e)*w.  q additionally folds 0.5*log2(e).
            const v2f y0 = (x[0]-x[1])*sn, y1 = (x[1]+x[0])*sn;
            const v2f y2 = (x[2]-x[3])*sn, y3 = (x[3]+x[2])*sn;
            const v2f y4 = (x[4]-x[5])*cs, y5 = (x[5]+x[4])*cs;
            const v2f y6 = (x[6]-x[7])*cs, y7 = (x[7]+x[6])*cs;
            if (wid == 0) {
                const int p = lane;                 // LINEAR pair slot
                float4* d = (float4*)sQ;
                d[2*p]       = make_float4(y0.x, y0.y, y1.x, y1.y);
                d[2*p+1]     = make_float4(y2.x, y2.y, y3.x, y3.y);
                d[104+2*p]   = make_float4(y4.x, y4.y, y5.x, y5.y);
                d[104+2*p+1] = make_float4(y6.x, y6.y, y7.x, y7.y);
            } else {
                const int i0 = PIDX(r0), i1 = PIDX(r0 + 1);
                float4* d = (float4*)sKV;           // K region
                d[i0]      = make_float4(y0.x, y1.x, y2.x, y3.x);
                d[SSP+i0]  = make_float4(y4.x, y5.x, y6.x, y7.x);
                d[i1]      = make_float4(y0.y, y1.y, y2.y, y3.y);
                d[SSP+i1]  = make_float4(y4.y, y5.y, y6.y, y7.y);
            }
        } else {
            const int i0 = PIDX(r0), i1 = PIDX(r0 + 1);
            float4* d = (float4*)sKV + 208;         // V region (832 floats in)
            d[i0]      = make_float4(x[0].x, x[1].x, x[2].x, x[3].x);
            d[SSP+i0]  = make_float4(x[4].x, x[5].x, x[6].x, x[7].x);
            d[i1]      = make_float4(x[0].y, x[1].y, x[2].y, x[3].y);
            d[SSP+i1]  = make_float4(x[4].y, x[5].y, x[6].y, x[7].y);
        }
    }
    __syncthreads();

    // ---------------- phase 2: attention, ALL 4 waves. wave = (head, q-half) -------------
    // lane = (qp, w): qp = lane>>2 (0..12) owns q-pairs {qh*26+2qp, +1} (4 rows);
    // w = lane&3 owns keys == w (mod 4).  INLINE-ASM SOFTWARE PIPELINE: the compiler
    // provably re-sinks C++ ds_reads (rounds 3/4: VGPR stuck at 36); volatile asm
    // ds_read_b128 + counted lgkmcnt + sched_barrier(0) [guide rule #18] forces a
    // 3-slot, 2-iteration-deep pipeline.  DS completes in-order, so lgkmcnt(8) with
    // 12 DS outstanding guarantees the oldest group of 4 is done (stray SMEM s_loads
    // only make the wait stricter).
    const int qp = lane >> 2, w = lane & 3;
    if (qp < 13) {
        const int h  = wid >> 1;
        const int qh = wid & 1;
        const int p0 = qh * 26 + 2 * qp;          // first of 2 pairs

        // LDS byte offsets: generic LDS ptr = aperture(hi32) | offset(lo32)
        const unsigned qb   = (unsigned)(size_t)&sQ[(h * 104 + 2 * p0) * 4];
        const unsigned base = (unsigned)(size_t)&sKV[(h * SSP + 13 * w) * HD];

        v4f qf0, qf1, qf2, qf3;
        v4f s0Ka, s0Kb, s0Va, s0Vb;
        v4f s1Ka, s1Kb, s1Va, s1Vb;
        v4f s2Ka, s2Kb, s2Va, s2Vb;

#define ISSUE(S, J) \
    asm volatile("ds_read_b128 %0, %1 offset:%2" : "=v"(s##S##Ka) : "v"(base), "n"((J)*16));        \
    asm volatile("ds_read_b128 %0, %1 offset:%2" : "=v"(s##S##Kb) : "v"(base), "n"(832 + (J)*16));  \
    asm volatile("ds_read_b128 %0, %1 offset:%2" : "=v"(s##S##Va) : "v"(base), "n"(3328 + (J)*16)); \
    asm volatile("ds_read_b128 %0, %1 offset:%2" : "=v"(s##S##Vb) : "v"(base), "n"(4160 + (J)*16))
#define DSW8 asm volatile("s_waitcnt lgkmcnt(8)"); __builtin_amdgcn_sched_barrier(0)
#define DSW4 asm volatile("s_waitcnt lgkmcnt(4)"); __builtin_amdgcn_sched_barrier(0)
#define DSW0 asm volatile("s_waitcnt lgkmcnt(0)"); __builtin_amdgcn_sched_barrier(0)

        // q loads also via asm so no compiler lgkm ops land inside the counted region
        asm volatile("ds_read_b128 %0, %1 offset:0"  : "=v"(qf0) : "v"(qb));
        asm volatile("ds_read_b128 %0, %1 offset:16" : "=v"(qf1) : "v"(qb));
        asm volatile("ds_read_b128 %0, %1 offset:32" : "=v"(qf2) : "v"(qb));
        asm volatile("ds_read_b128 %0, %1 offset:48" : "=v"(qf3) : "v"(qb));
        ISSUE(0, 0); ISSUE(1, 1);
        DSW8;                                   // 12 outstanding -> q's 4 done
        v2f q[2][4];
        q[0][0] = (v2f){qf0.x, qf0.y}; q[0][1] = (v2f){qf0.z, qf0.w};
        q[0][2] = (v2f){qf1.x, qf1.y}; q[0][3] = (v2f){qf1.z, qf1.w};
        q[1][0] = (v2f){qf2.x, qf2.y}; q[1][1] = (v2f){qf2.z, qf2.w};
        q[1][2] = (v2f){qf3.x, qf3.y}; q[1][3] = (v2f){qf3.z, qf3.w};

        v2f acc[2][4], l[2];
#pragma unroll
        for (int P = 0; P < 2; ++P) {
            l[P] = (v2f){0.f, 0.f};
#pragma unroll
            for (int d = 0; d < 4; ++d) acc[P][d] = (v2f){0.f, 0.f};
        }

#define HALF(KK, VV) { \
    _Pragma("unroll") \
    for (int P = 0; P < 2; ++P) { \
        v2f sxy = q[P][0]*(KK).x + q[P][1]*(KK).y + q[P][2]*(KK).z + q[P][3]*(KK).w; \
        v2f p; p.x = __builtin_amdgcn_exp2f(sxy.x); p.y = __builtin_amdgcn_exp2f(sxy.y); \
        l[P] += p; \
        acc[P][0] += p*(VV).x; acc[P][1] += p*(VV).y; \
        acc[P][2] += p*(VV).z; acc[P][3] += p*(VV).w; \
    } }
#define BODY(S) HALF(s##S##Ka, s##S##Va) HALF(s##S##Kb, s##S##Vb)

        ISSUE(2, 2);  DSW8; BODY(0);   // j=0
        ISSUE(0, 3);  DSW8; BODY(1);   // j=1
        ISSUE(1, 4);  DSW8; BODY(2);   // j=2
        ISSUE(2, 5);  DSW8; BODY(0);   // j=3
        ISSUE(0, 6);  DSW8; BODY(1);   // j=4
        ISSUE(1, 7);  DSW8; BODY(2);   // j=5
        ISSUE(2, 8);  DSW8; BODY(0);   // j=6
        ISSUE(0, 9);  DSW8; BODY(1);   // j=7
        ISSUE(1, 10); DSW8; BODY(2);   // j=8
        ISSUE(2, 11); DSW8; BODY(0);   // j=9
        ISSUE(0, 12); DSW8; BODY(1);   // j=10
                      DSW4; BODY(2);   // j=11
                      DSW0; BODY(0);   // j=12

#undef ISSUE
#undef DSW8
#undef DSW4
#undef DSW0
#undef HALF
#undef BODY
        // pad keys 102,103 (zero K rows, exp2(0)=1) landed in residues w=2,3 via Kb j=12
        if (w >= 2) { l[0] -= (v2f){1.f, 1.f}; l[1] -= (v2f){1.f, 1.f}; }
        // quad butterfly over the 4 key residues (pure VALU, no LDS round-trip)
#pragma unroll
        for (int P = 0; P < 2; ++P) {
            l[P] += dpp2<0xB1>(l[P]);                       // quad_perm [1,0,3,2]
#pragma unroll
            for (int d = 0; d < 4; ++d) acc[P][d] += dpp2<0xB1>(acc[P][d]);
        }
#pragma unroll
        for (int P = 0; P < 2; ++P) {
            l[P] += dpp2<0x4E>(l[P]);                       // quad_perm [2,3,0,1]
#pragma unroll
            for (int d = 0; d < 4; ++d) acc[P][d] += dpp2<0x4E>(acc[P][d]);
        }
        // lane w==0 writes pair 0, w==1 writes pair 1 (static branches)
        float4* comb = (float4*)sC + h * SSP;
#define WRITE_PAIR(P) { \
            const int r0 = 2 * (p0 + (P)); \
            if (r0 < SS) { \
                const float ix = 1.f / l[P].x; \
                comb[r0] = make_float4(acc[P][0].x*ix, acc[P][1].x*ix, \
                                       acc[P][2].x*ix, acc[P][3].x*ix); \
            } \
            if (r0 + 1 < SS) { \
                const float iy = 1.f / l[P].y; \
                comb[r0+1] = make_float4(acc[P][0].y*iy, acc[P][1].y*iy, \
                                         acc[P][2].y*iy, acc[P][3].y*iy); \
            } \
        }
        if      (w == 0) WRITE_PAIR(0)
        else if (w == 1) WRITE_PAIR(1)
#undef WRITE_PAIR
    }
    __syncthreads();

    // ---------------- phase 3: output projection (wo in SGPRs) ----------------
    const int row = wid * 26 + lane;
    if (lane < 26 && row < SS) {
        const float4 c0 = ((const float4*)sC)[row];        // head 0
        const float4 c1 = ((const float4*)sC)[SSP + row];  // head 1
        float o[8];
#pragma unroll
        for (int i = 0; i < 8; ++i) {
            const float* wr = wo + i*8;
            o[i] = c0.x*wr[0] + c0.y*wr[1] + c0.z*wr[2] + c0.w*wr[3]
                 + c1.x*wr[4] + c1.y*wr[5] + c1.z*wr[6] + c1.w*wr[7];
        }
        float4* o4 = (float4*)(out + (size_t)b * (SS * HID) + row * HID);
        o4[0] = make_float4(o[0], o[1], o[2], o[3]);
        o4[1] = make_float4(o[4], o[5], o[6], o[7]);
    }
}

extern "C" void kernel_launch(void* const* d_in, const int* in_sizes, int n_in,
                              void* d_out, int out_size, void* d_ws, size_t ws_size,
                              hipStream_t stream) {
    const float* query = (const float*)d_in[0];
    const float* key   = (const float*)d_in[1];
    const float* value = (const float*)d_in[2];
    const float* wq    = (const float*)d_in[3];
    const float* wk    = (const float*)d_in[4];
    const float* wv    = (const float*)d_in[5];
    const float* wo    = (const float*)d_in[6];
    float* out = (float*)d_out;
    mha_fused_kernel<<<NB, 256, 0, stream>>>(query, key, value, wq, wk, wv, wo, out);
}

// Round 6
// 121.483 us; speedup vs baseline: 1.1606x; 1.0683x over previous
//
#include <hip/hip_runtime.h>

#define NB 4096
#define SS 102
#define SSP 104    // q rows padded to a multiple of 2 lanes*2
#define HID 8      // HIDDEN
#define NH 2       // HEADS
#define HD 4       // HEAD_DIM

typedef float v2f __attribute__((ext_vector_type(2)));

// LDS layout:
//  sRaw : [3][102][8] raw q/k/v rows.
//         After the projections this region is dead and is reused for the
//         attention partials of BOTH k-halves:
//           [0..1664)    acc partials as [kh*2+h][row][4] float4 records
//           [1664..2080) l partials as [kh*2+h][row]
//  sQ   : [2][104][4] rotated+pre-scaled q (rows 102,103 zero pad)
//  sK   : [2][102][4] rotated k
//  sV   : [2][102][4] projected v
//  sW   : [4][64] wq, wk, wv, wo
//  sRot : sin(s) at [0..102), cos(s) at [102..204)
__global__ __launch_bounds__(256) void mha_fused_kernel(
    const float* __restrict__ query, const float* __restrict__ key,
    const float* __restrict__ value, const float* __restrict__ wq,
    const float* __restrict__ wk, const float* __restrict__ wv,
    const float* __restrict__ wo, float* __restrict__ out)
{
    __shared__ float sRaw[3 * SS * HID];     // 2448
    __shared__ float sQ[NH * SSP * HD];      // 832
    __shared__ float sK[NH * SS * HD];       // 816
    __shared__ float sV[NH * SS * HD];       // 816
    __shared__ float sW[4 * 64];             // 256
    __shared__ float sRot[2 * SS];           // 204

    const int t = threadIdx.x;
    const int b = blockIdx.x;

    // ---- issue all global loads into registers first ----
    float4 rq, rk, rv;
    if (t < 204) {
        const float4* q4 = (const float4*)(query + (size_t)b * (SS * HID));
        const float4* k4 = (const float4*)(key   + (size_t)b * (SS * HID));
        const float4* v4 = (const float4*)(value + (size_t)b * (SS * HID));
        rq = q4[t]; rk = k4[t]; rv = v4[t];
    }
    float wreg;
    {
        const float* wsrc = (t < 64) ? wq : (t < 128) ? wk : (t < 192) ? wv : wo;
        wreg = wsrc[t & 63];
    }

    // ---- sin/cos table via native trig (v_sin/v_cos, ~3 insts vs ~50 libm):
    //      overlaps the global-load latency (no data dep) ----
    if (t < SS)                    sRot[t] = __sinf((float)t);
    else if (t >= 128 && t < 230)  sRot[SS + (t - 128)] = __cosf((float)(t - 128));

    // ---- zero-pad q rows 102,103 (both heads) ----
    if (t >= 230 && t < 246) {
        const int z = t - 230;                // 0..15
        const int h = z >> 3, r = SS + ((z >> 2) & 1), d = z & 3;
        sQ[h * SSP * HD + r * HD + d] = 0.f;
    }

    // ---- commit staged data to LDS ----
    sW[t] = wreg;
    if (t < 204) {
        float4* sRaw4 = (float4*)sRaw;
        sRaw4[t]       = rq;
        sRaw4[204 + t] = rk;
        sRaw4[408 + t] = rv;
    }
    __syncthreads();

    // ---- q/k projection + fused rotary (816 pair-items) ----
    // reference broadcast quirk: head 0 scaled by sin(s), head 1 by cos(s);
    // rotary pair: out_even=(x_even-x_odd)*w, out_odd=(x_odd+x_even)*w.
    // q additionally folds 0.5 (score scale) * log2(e) so softmax can use
    // raw v_exp_f32 (base-2).
    for (int p = t; p < 816; p += 256) {
        const int tensor = (p >= 408) ? 1 : 0;   // 0 = q, 1 = k (no div)
        const int pp = tensor ? (p - 408) : p;
        const int s  = pp >> 2;
        const int pr = pp & 3;
        const int i0 = pr * 2, i1 = i0 + 1;
        const float4* raw4 = (const float4*)(sRaw + tensor * (SS * HID) + s * HID);
        const float4 ra = raw4[0], rb = raw4[1];
        const float4* w0 = (const float4*)(sW + tensor * 64 + i0 * 8);
        const float4 wa = w0[0], wb = w0[1], wc = w0[2], wd = w0[3];
        float x0 = ra.x * wa.x + ra.y * wa.y + ra.z * wa.z + ra.w * wa.w
                 + rb.x * wb.x + rb.y * wb.y + rb.z * wb.z + rb.w * wb.w;
        float x1 = ra.x * wc.x + ra.y * wc.y + ra.z * wc.z + ra.w * wc.w
                 + rb.x * wd.x + rb.y * wd.y + rb.z * wd.z + rb.w * wd.w;
        const int h = pr >> 1;
        float wr = sRot[h * SS + s];
        if (tensor == 0) wr *= 0.72134752044448170368f;  // 0.5 * log2(e)
        const float r0 = (x0 - x1) * wr;
        const float r1 = (x1 + x0) * wr;
        const int d0 = i0 & 3;
        float* dst = (tensor == 0)
            ? (sQ + h * SSP * HD + s * HD + d0)
            : (sK + h * SS * HD + s * HD + d0);
        dst[0] = r0;
        dst[1] = r1;
    }
    // ---- v projection ----
    for (int e = t; e < 816; e += 256) {
        const int s = e >> 3, i = e & 7;
        const float4* raw4 = (const float4*)(sRaw + 2 * (SS * HID) + s * HID);
        const float4 ra = raw4[0], rb = raw4[1];
        const float4* w0 = (const float4*)(sW + 2 * 64 + i * 8);
        const float4 wa = w0[0], wb = w0[1];
        const float x = ra.x * wa.x + ra.y * wa.y + ra.z * wa.z + ra.w * wa.w
                      + rb.x * wb.x + rb.y * wb.y + rb.z * wb.z + rb.w * wb.w;
        const int h = i >> 2, d = i & 3;
        sV[h * SS * HD + s * HD + d] = x;
    }
    __syncthreads();

    // ---- attention: ALL 4 waves. wave = h*2 + khalf.
    // Each wave handles one head and one half of the k range (51 keys).
    // Each lane owns 2 q-rows (52 active lanes -> 104 padded rows),
    // packed as float2 so the compiler can emit v_pk_fma_f32.
    const int wv_  = t >> 6, lane = t & 63;
    const int h    = wv_ >> 1;
    const int kh   = wv_ & 1;
    const bool act = lane < 52;
    v2f acc0 = {0.f, 0.f}, acc1 = {0.f, 0.f}, acc2 = {0.f, 0.f}, acc3 = {0.f, 0.f};
    v2f l = {0.f, 0.f};
    if (act) {
        const float* qb = sQ + h * SSP * HD + (2 * lane) * HD;
        const float4 qa = ((const float4*)qb)[0];
        const float4 qc = ((const float4*)qb)[1];
        const v2f q0 = {qa.x, qc.x}, q1 = {qa.y, qc.y},
                  q2 = {qa.z, qc.z}, q3 = {qa.w, qc.w};
        const float4* K4 = (const float4*)(sK + h * SS * HD) + kh * 51;
        const float4* V4 = (const float4*)(sV + h * SS * HD) + kh * 51;
        // register-rotating prefetch: load k+1 while computing k
        float4 kk = K4[0], vvv = V4[0];
#pragma unroll 2
        for (int k = 1; k < 51; ++k) {
            const float4 nk = K4[k], nv = V4[k];
            v2f s = q0 * kk.x + q1 * kk.y + q2 * kk.z + q3 * kk.w;
            v2f p;
            p.x = __builtin_amdgcn_exp2f(s.x);
            p.y = __builtin_amdgcn_exp2f(s.y);
            l += p;
            acc0 += p * vvv.x; acc1 += p * vvv.y;
            acc2 += p * vvv.z; acc3 += p * vvv.w;
            kk = nk; vvv = nv;
        }
        {
            v2f s = q0 * kk.x + q1 * kk.y + q2 * kk.z + q3 * kk.w;
            v2f p;
            p.x = __builtin_amdgcn_exp2f(s.x);
            p.y = __builtin_amdgcn_exp2f(s.y);
            l += p;
            acc0 += p * vvv.x; acc1 += p * vvv.y;
            acc2 += p * vvv.z; acc3 += p * vvv.w;
        }
    }
    // ---- publish: BOTH halves write raw partials into the dead sRaw region.
    // acc as float4 records [kh*2+h][row][4] at [0..1664), l at [1664..2080).
    // (raw-input reads all completed before the previous barrier)
    if (act) {
        const int rec = kh * 2 + h;
        float4* A4 = (float4*)sRaw + rec * SSP + 2 * lane;
        A4[0] = make_float4(acc0.x, acc1.x, acc2.x, acc3.x);
        A4[1] = make_float4(acc0.y, acc1.y, acc2.y, acc3.y);
        float* L = sRaw + 4 * SSP * 4 + rec * SSP + 2 * lane;
        L[0] = l.x; L[1] = l.y;
    }
    __syncthreads();

    // ---- output projection with inline combine+normalize (wo from LDS) ----
    // comb[s][j] = (accA[j]+accB[j]) / (lA+lB), per head; then dot with wo row i.
    for (int e = t; e < 816; e += 256) {
        const int s = e >> 3, i = e & 7;
        const float4* A4 = (const float4*)sRaw;
        const float4 h0a = A4[0 * SSP + s], h0b = A4[2 * SSP + s];  // head0: kh=0,1
        const float4 h1a = A4[1 * SSP + s], h1b = A4[3 * SSP + s];  // head1: kh=0,1
        const float* L = sRaw + 4 * SSP * 4;
        const float inv0 = 1.f / (L[0 * SSP + s] + L[2 * SSP + s]);
        const float inv1 = 1.f / (L[1 * SSP + s] + L[3 * SSP + s]);
        const float c0 = (h0a.x + h0b.x) * inv0, c1 = (h0a.y + h0b.y) * inv0;
        const float c2 = (h0a.z + h0b.z) * inv0, c3 = (h0a.w + h0b.w) * inv0;
        const float c4 = (h1a.x + h1b.x) * inv1, c5 = (h1a.y + h1b.y) * inv1;
        const float c6 = (h1a.z + h1b.z) * inv1, c7 = (h1a.w + h1b.w) * inv1;
        const float4* w0 = (const float4*)(sW + 3 * 64 + i * 8);
        const float4 wa = w0[0], wb = w0[1];
        const float x = c0 * wa.x + c1 * wa.y + c2 * wa.z + c3 * wa.w
                      + c4 * wb.x + c5 * wb.y + c6 * wb.z + c7 * wb.w;
        out[(size_t)b * (SS * HID) + e] = x;
    }
}

extern "C" void kernel_launch(void* const* d_in, const int* in_sizes, int n_in,
                              void* d_out, int out_size, void* d_ws, size_t ws_size,
                              hipStream_t stream) {
    const float* query = (const float*)d_in[0];
    const float* key   = (const float*)d_in[1];
    const float* value = (const float*)d_in[2];
    const float* wq    = (const float*)d_in[3];
    const float* wk    = (const float*)d_in[4];
    const float* wv    = (const float*)d_in[5];
    const float* wo    = (const float*)d_in[6];
    float* out = (float*)d_out;
    mha_fused_kernel<<<NB, 256, 0, stream>>>(query, key, value, wq, wk, wv, wo, out);
}